// Round 5
// baseline (685.374 us; speedup 1.0000x reference)
//
#include <hip/hip_runtime.h>

#define N_NODES 50000
#define N_EDGES 800000
#define CH 96
#define C4 24          // CH / 4 float4s per row
#define STEPS 10

// ---------- CSR build ----------

__global__ void count_deg(const int* __restrict__ ei, int* __restrict__ deg, int ne) {
    int e = blockIdx.x * blockDim.x + threadIdx.x;
    if (e < ne) {
        int d = ei[ne + e];   // dst row of edge_index (int32 per harness)
        if ((unsigned)d < (unsigned)N_NODES) atomicAdd(&deg[d], 1);
    }
}

__global__ void compute_dinv(const int* __restrict__ deg, float* __restrict__ dinv, int n) {
    int i = blockIdx.x * blockDim.x + threadIdx.x;
    if (i < n) {
        int d = deg[i];
        dinv[i] = (d > 0) ? (1.0f / sqrtf((float)d)) : 0.0f;
    }
}

// hierarchical exclusive scan of deg -> row_ptr (3 kernels, 256-wide chunks)
__global__ void scan1(const int* __restrict__ deg, int* __restrict__ row_ptr,
                      int* __restrict__ partials, int n) {
    __shared__ int sm[256];
    int i = blockIdx.x * 256 + threadIdx.x;
    int v = (i < n) ? deg[i] : 0;
    sm[threadIdx.x] = v;
    __syncthreads();
    for (int off = 1; off < 256; off <<= 1) {
        int t = (threadIdx.x >= off) ? sm[threadIdx.x - off] : 0;
        __syncthreads();
        sm[threadIdx.x] += t;
        __syncthreads();
    }
    if (i < n) row_ptr[i + 1] = sm[threadIdx.x];          // inclusive within chunk
    if (threadIdx.x == 255) partials[blockIdx.x] = sm[255];
}

__global__ void scan2(int* __restrict__ partials, int nb) {
    __shared__ int sm[256];
    int v = (threadIdx.x < nb) ? partials[threadIdx.x] : 0;
    sm[threadIdx.x] = v;
    __syncthreads();
    for (int off = 1; off < 256; off <<= 1) {
        int t = (threadIdx.x >= off) ? sm[threadIdx.x - off] : 0;
        __syncthreads();
        sm[threadIdx.x] += t;
        __syncthreads();
    }
    if (threadIdx.x < nb) partials[threadIdx.x] = sm[threadIdx.x] - v;  // exclusive
}

__global__ void scan3(int* __restrict__ row_ptr, const int* __restrict__ partials, int n) {
    int i = blockIdx.x * 256 + threadIdx.x;
    if (i < n) row_ptr[i + 1] += partials[blockIdx.x];
    if (i == 0) row_ptr[0] = 0;
}

// packed CSR entry: .x = src index, .y = float bits of norm (one 8B store/edge).
// deg doubles as the fill cursor via atomicSub (slots deg-1..0).
__global__ void fill_csr(const int* __restrict__ ei, const int* __restrict__ row_ptr,
                         int* __restrict__ deg, const float* __restrict__ dinv,
                         int2* __restrict__ csr_pack, int ne) {
    int e = blockIdx.x * blockDim.x + threadIdx.x;
    if (e < ne) {
        int s = ei[e];
        int d = ei[ne + e];
        if ((unsigned)s >= (unsigned)N_NODES || (unsigned)d >= (unsigned)N_NODES) return;
        int slot = atomicSub(&deg[d], 1) - 1;
        int pos = row_ptr[d] + slot;
        csr_pack[pos] = make_int2(s, __float_as_int(dinv[s] * dinv[d]));
    }
}

// ---------- propagation ----------
// one thread per (node, channel-quad). Edge loop in blocks of 8 with explicit
// two-stage pipeline: while 8 gathers are in flight, the next block's 8 CSR
// entries are loaded -> ~8 outstanding gathers/wave, meta latency hidden.
// k==0 fuses out = gamma0*x + gamma1*acc; k==STEPS-1 skips the h_out write.
__global__ __launch_bounds__(256) void prop(const float* __restrict__ h_in,
                                            float* __restrict__ h_out,
                                            float* __restrict__ out,
                                            const int* __restrict__ row_ptr,
                                            const int2* __restrict__ csr_pack,
                                            const float* __restrict__ gamma, int k) {
    int g = blockIdx.x * blockDim.x + threadIdx.x;
    if (g >= N_NODES * C4) return;
    int node = g / C4;
    int c4   = g - node * C4;
    int beg = row_ptr[node];
    int end = row_ptr[node + 1];
    const float4* __restrict__ hin4 = (const float4*)h_in;

    float4 a0 = make_float4(0.f, 0.f, 0.f, 0.f);
    float4 a1 = a0, a2 = a0, a3 = a0;

    int nfull = (end - beg) >> 3;
    int e = beg;
    if (nfull > 0) {
        int2 m0 = csr_pack[e];     int2 m1 = csr_pack[e + 1];
        int2 m2 = csr_pack[e + 2]; int2 m3 = csr_pack[e + 3];
        int2 m4 = csr_pack[e + 4]; int2 m5 = csr_pack[e + 5];
        int2 m6 = csr_pack[e + 6]; int2 m7 = csr_pack[e + 7];
        for (int b = 0; b < nfull; ++b) {
            // issue 8 independent gathers with current metadata
            float4 h0 = hin4[m0.x * C4 + c4];
            float4 h1 = hin4[m1.x * C4 + c4];
            float4 h2 = hin4[m2.x * C4 + c4];
            float4 h3 = hin4[m3.x * C4 + c4];
            float4 h4 = hin4[m4.x * C4 + c4];
            float4 h5 = hin4[m5.x * C4 + c4];
            float4 h6 = hin4[m6.x * C4 + c4];
            float4 h7 = hin4[m7.x * C4 + c4];
            float w0 = __int_as_float(m0.y), w1 = __int_as_float(m1.y);
            float w2 = __int_as_float(m2.y), w3 = __int_as_float(m3.y);
            float w4 = __int_as_float(m4.y), w5 = __int_as_float(m5.y);
            float w6 = __int_as_float(m6.y), w7 = __int_as_float(m7.y);
            e += 8;
            if (b + 1 < nfull) {   // prefetch next block's metadata (overlaps gathers)
                m0 = csr_pack[e];     m1 = csr_pack[e + 1];
                m2 = csr_pack[e + 2]; m3 = csr_pack[e + 3];
                m4 = csr_pack[e + 4]; m5 = csr_pack[e + 5];
                m6 = csr_pack[e + 6]; m7 = csr_pack[e + 7];
            }
            a0.x = fmaf(w0, h0.x, a0.x); a0.y = fmaf(w0, h0.y, a0.y);
            a0.z = fmaf(w0, h0.z, a0.z); a0.w = fmaf(w0, h0.w, a0.w);
            a1.x = fmaf(w1, h1.x, a1.x); a1.y = fmaf(w1, h1.y, a1.y);
            a1.z = fmaf(w1, h1.z, a1.z); a1.w = fmaf(w1, h1.w, a1.w);
            a2.x = fmaf(w2, h2.x, a2.x); a2.y = fmaf(w2, h2.y, a2.y);
            a2.z = fmaf(w2, h2.z, a2.z); a2.w = fmaf(w2, h2.w, a2.w);
            a3.x = fmaf(w3, h3.x, a3.x); a3.y = fmaf(w3, h3.y, a3.y);
            a3.z = fmaf(w3, h3.z, a3.z); a3.w = fmaf(w3, h3.w, a3.w);
            a0.x = fmaf(w4, h4.x, a0.x); a0.y = fmaf(w4, h4.y, a0.y);
            a0.z = fmaf(w4, h4.z, a0.z); a0.w = fmaf(w4, h4.w, a0.w);
            a1.x = fmaf(w5, h5.x, a1.x); a1.y = fmaf(w5, h5.y, a1.y);
            a1.z = fmaf(w5, h5.z, a1.z); a1.w = fmaf(w5, h5.w, a1.w);
            a2.x = fmaf(w6, h6.x, a2.x); a2.y = fmaf(w6, h6.y, a2.y);
            a2.z = fmaf(w6, h6.z, a2.z); a2.w = fmaf(w6, h6.w, a2.w);
            a3.x = fmaf(w7, h7.x, a3.x); a3.y = fmaf(w7, h7.y, a3.y);
            a3.z = fmaf(w7, h7.z, a3.z); a3.w = fmaf(w7, h7.w, a3.w);
        }
    }
    for (; e < end; ++e) {
        int2 m = csr_pack[e];
        float4 hv = hin4[m.x * C4 + c4];
        float w = __int_as_float(m.y);
        a0.x = fmaf(w, hv.x, a0.x); a0.y = fmaf(w, hv.y, a0.y);
        a0.z = fmaf(w, hv.z, a0.z); a0.w = fmaf(w, hv.w, a0.w);
    }
    float4 acc;
    acc.x = (a0.x + a1.x) + (a2.x + a3.x);
    acc.y = (a0.y + a1.y) + (a2.y + a3.y);
    acc.z = (a0.z + a1.z) + (a2.z + a3.z);
    acc.w = (a0.w + a1.w) + (a2.w + a3.w);

    float gk = gamma[k + 1];
    float4 o;
    if (k == 0) {
        float g0 = gamma[0];
        float4 xo = hin4[g];          // h_in == x at k==0
        o.x = fmaf(gk, acc.x, g0 * xo.x);
        o.y = fmaf(gk, acc.y, g0 * xo.y);
        o.z = fmaf(gk, acc.z, g0 * xo.z);
        o.w = fmaf(gk, acc.w, g0 * xo.w);
    } else {
        o = ((float4*)out)[g];
        o.x = fmaf(gk, acc.x, o.x);
        o.y = fmaf(gk, acc.y, o.y);
        o.z = fmaf(gk, acc.z, o.z);
        o.w = fmaf(gk, acc.w, o.w);
    }
    ((float4*)out)[g] = o;
    if (k != STEPS - 1) {
        ((float4*)h_out)[g] = acc;
    }
}

// ---------- launch ----------

static inline size_t align_up(size_t v, size_t a) { return (v + a - 1) & ~(a - 1); }

extern "C" void kernel_launch(void* const* d_in, const int* in_sizes, int n_in,
                              void* d_out, int out_size, void* d_ws, size_t ws_size,
                              hipStream_t stream) {
    const float* x     = (const float*)d_in[0];
    const int*   ei    = (const int*)d_in[1];      // int32 per harness conversion
    const float* gamma = (const float*)d_in[2];
    float*       out   = (float*)d_out;

    const int n  = N_NODES;
    const int ne = N_EDGES;
    const int nblk_nodes = (n + 255) / 256;          // 196

    // workspace carve-up (256B aligned), total ~46 MB
    char*  ws  = (char*)d_ws;
    size_t off = 0;
    int*   deg      = (int*)(ws + off);   off = align_up(off + (size_t)n * 4, 256);
    int*   row_ptr  = (int*)(ws + off);   off = align_up(off + (size_t)(n + 1) * 4, 256);
    int*   partials = (int*)(ws + off);   off = align_up(off + (size_t)nblk_nodes * 4, 256);
    float* dinv     = (float*)(ws + off); off = align_up(off + (size_t)n * 4, 256);
    int2*  csr_pack = (int2*)(ws + off);  off = align_up(off + (size_t)ne * 8, 256);
    float* hA       = (float*)(ws + off); off = align_up(off + (size_t)n * CH * 4, 256);
    float* hB       = (float*)(ws + off); off = align_up(off + (size_t)n * CH * 4, 256);
    (void)ws_size;

    (void)hipMemsetAsync(deg, 0, (size_t)n * 4, stream);

    const int nblk_edges = (ne + 255) / 256;         // 3125
    count_deg<<<nblk_edges, 256, 0, stream>>>(ei, deg, ne);
    compute_dinv<<<nblk_nodes, 256, 0, stream>>>(deg, dinv, n);

    scan1<<<nblk_nodes, 256, 0, stream>>>(deg, row_ptr, partials, n);
    scan2<<<1, 256, 0, stream>>>(partials, nblk_nodes);
    scan3<<<nblk_nodes, 256, 0, stream>>>(row_ptr, partials, n);

    fill_csr<<<nblk_edges, 256, 0, stream>>>(ei, row_ptr, deg, dinv, csr_pack, ne);

    const int n4 = n * C4;                            // 1.2M float4s
    const int nblk_n4 = (n4 + 255) / 256;             // 4688

    const float* hin = x;
    float* hout = hA;
    for (int k = 0; k < STEPS; ++k) {
        prop<<<nblk_n4, 256, 0, stream>>>(hin, hout, out, row_ptr, csr_pack, gamma, k);
        hin  = hout;
        hout = (hout == hA) ? hB : hA;
    }
}

// Round 6
// 627.656 us; speedup vs baseline: 1.0920x; 1.0920x over previous
//
#include <hip/hip_runtime.h>

#define N_NODES 50000
#define N_EDGES 800000
#define CH 96
#define C4 24          // CH / 4 float4s per row
#define STEPS 10
#define SENT N_NODES   // sentinel src row (kept all-zero in both p buffers)

// ---------- CSR build ----------

// 4 edges per thread, vectorized dst read
__global__ void count_deg(const int* __restrict__ ei, int* __restrict__ deg, int ne) {
    int t = blockIdx.x * blockDim.x + threadIdx.x;
    int e = t * 4;
    if (e < ne) {
        int4 d4 = *(const int4*)(ei + ne + e);
        if ((unsigned)d4.x < (unsigned)N_NODES) atomicAdd(&deg[d4.x], 1);
        if ((unsigned)d4.y < (unsigned)N_NODES) atomicAdd(&deg[d4.y], 1);
        if ((unsigned)d4.z < (unsigned)N_NODES) atomicAdd(&deg[d4.z], 1);
        if ((unsigned)d4.w < (unsigned)N_NODES) atomicAdd(&deg[d4.w], 1);
    }
}

// scan1 also computes dinv; row_ptr is built over PADDED degrees (round up to 4)
__global__ void scan1(const int* __restrict__ deg, int* __restrict__ row_ptr,
                      int* __restrict__ partials, float* __restrict__ dinv, int n) {
    __shared__ int sm[256];
    int i = blockIdx.x * 256 + threadIdx.x;
    int v = 0;
    if (i < n) {
        int d = deg[i];
        dinv[i] = (d > 0) ? (1.0f / sqrtf((float)d)) : 0.0f;
        v = (d + 3) & ~3;                      // padded degree
    }
    sm[threadIdx.x] = v;
    __syncthreads();
    for (int off = 1; off < 256; off <<= 1) {
        int t = (threadIdx.x >= off) ? sm[threadIdx.x - off] : 0;
        __syncthreads();
        sm[threadIdx.x] += t;
        __syncthreads();
    }
    if (i < n) row_ptr[i + 1] = sm[threadIdx.x];          // inclusive within chunk
    if (threadIdx.x == 255) partials[blockIdx.x] = sm[255];
}

__global__ void scan2(int* __restrict__ partials, int nb) {
    __shared__ int sm[256];
    int v = (threadIdx.x < nb) ? partials[threadIdx.x] : 0;
    sm[threadIdx.x] = v;
    __syncthreads();
    for (int off = 1; off < 256; off <<= 1) {
        int t = (threadIdx.x >= off) ? sm[threadIdx.x - off] : 0;
        __syncthreads();
        sm[threadIdx.x] += t;
        __syncthreads();
    }
    if (threadIdx.x < nb) partials[threadIdx.x] = sm[threadIdx.x] - v;  // exclusive
}

__global__ void scan3(int* __restrict__ row_ptr, const int* __restrict__ partials, int n) {
    int i = blockIdx.x * 256 + threadIdx.x;
    if (i < n) row_ptr[i + 1] += partials[blockIdx.x];
    if (i == 0) row_ptr[0] = 0;
}

// fill pad slots [deg, deg_padded) with sentinel BEFORE fill_csr consumes deg
__global__ void pad_fill(const int* __restrict__ deg, const int* __restrict__ row_ptr,
                         int* __restrict__ csr_src, int n) {
    int i = blockIdx.x * blockDim.x + threadIdx.x;
    if (i < n) {
        int dg = deg[i];
        int dp = (dg + 3) & ~3;
        int base = row_ptr[i];
        for (int j = dg; j < dp; ++j) csr_src[base + j] = SENT;
    }
}

// scatter src into dst-grouped slots; deg doubles as cursor via atomicSub
__global__ void fill_csr(const int* __restrict__ ei, const int* __restrict__ row_ptr,
                         int* __restrict__ deg, int* __restrict__ csr_src, int ne) {
    int t = blockIdx.x * blockDim.x + threadIdx.x;
    int e = t * 4;
    if (e < ne) {
        int4 s4 = *(const int4*)(ei + e);
        int4 d4 = *(const int4*)(ei + ne + e);
        #pragma unroll
        for (int j = 0; j < 4; ++j) {
            int s = (j == 0) ? s4.x : (j == 1) ? s4.y : (j == 2) ? s4.z : s4.w;
            int d = (j == 0) ? d4.x : (j == 1) ? d4.y : (j == 2) ? d4.z : d4.w;
            if ((unsigned)d >= (unsigned)N_NODES) continue;
            if ((unsigned)s >= (unsigned)N_NODES) s = SENT;   // keep slot consistent
            int slot = atomicSub(&deg[d], 1) - 1;
            csr_src[row_ptr[d] + slot] = s;
        }
    }
}

// p0 = dinv ⊙ x ; also zero the sentinel row in BOTH p buffers
__global__ void prescale(const float* __restrict__ x, const float* __restrict__ dinv,
                         float* __restrict__ pA, float* __restrict__ pB) {
    int g = blockIdx.x * blockDim.x + threadIdx.x;
    const int n4 = N_NODES * C4;
    if (g < n4) {
        float dv = dinv[g / C4];
        float4 v = ((const float4*)x)[g];
        ((float4*)pA)[g] = make_float4(dv * v.x, dv * v.y, dv * v.z, dv * v.w);
    } else if (g < n4 + C4) {
        float4 z = make_float4(0.f, 0.f, 0.f, 0.f);
        ((float4*)pA)[g] = z;
        ((float4*)pB)[g] = z;
    }
}

// ---------- propagation ----------
// p_in = dinv ⊙ h_k. S = sum_e p_in[src]; h_{k+1} = dinv[node]*S;
// out += gamma[k+1]*h_{k+1}; p_out = dinv[node]*h_{k+1}.
// Edge counts are padded to x4 (sentinel rows are zero) -> no remainder loop.
// k==0 fuses out = gamma0*x + gamma1*h1; k==STEPS-1 skips the p_out write.
__global__ __launch_bounds__(256) void prop(const float* __restrict__ p_in,
                                            float* __restrict__ p_out,
                                            float* __restrict__ out,
                                            const float* __restrict__ x,
                                            const int* __restrict__ row_ptr,
                                            const int* __restrict__ csr_src,
                                            const float* __restrict__ dinv,
                                            const float* __restrict__ gamma, int k) {
    int g = blockIdx.x * blockDim.x + threadIdx.x;
    if (g >= N_NODES * C4) return;
    int node = g / C4;
    int c4   = g - node * C4;
    int beg = row_ptr[node];
    int end = row_ptr[node + 1];          // (end-beg) % 4 == 0 by construction
    const float4* __restrict__ pin4 = (const float4*)p_in;

    float4 a0 = make_float4(0.f, 0.f, 0.f, 0.f);
    float4 a1 = a0, a2 = a0, a3 = a0;

    for (int e = beg; e < end; e += 4) {
        int4 m = *(const int4*)(csr_src + e);     // 4 src indices, one 16B load
        float4 h0 = pin4[m.x * C4 + c4];
        float4 h1 = pin4[m.y * C4 + c4];
        float4 h2 = pin4[m.z * C4 + c4];
        float4 h3 = pin4[m.w * C4 + c4];
        a0.x += h0.x; a0.y += h0.y; a0.z += h0.z; a0.w += h0.w;
        a1.x += h1.x; a1.y += h1.y; a1.z += h1.z; a1.w += h1.w;
        a2.x += h2.x; a2.y += h2.y; a2.z += h2.z; a2.w += h2.w;
        a3.x += h3.x; a3.y += h3.y; a3.z += h3.z; a3.w += h3.w;
    }
    float4 S;
    S.x = (a0.x + a1.x) + (a2.x + a3.x);
    S.y = (a0.y + a1.y) + (a2.y + a3.y);
    S.z = (a0.z + a1.z) + (a2.z + a3.z);
    S.w = (a0.w + a1.w) + (a2.w + a3.w);

    float dv = dinv[node];
    float4 h;                                   // h_{k+1} row slice
    h.x = dv * S.x; h.y = dv * S.y; h.z = dv * S.z; h.w = dv * S.w;

    float gk = gamma[k + 1];
    float4 o;
    if (k == 0) {
        float g0 = gamma[0];
        float4 xo = ((const float4*)x)[g];
        o.x = fmaf(gk, h.x, g0 * xo.x);
        o.y = fmaf(gk, h.y, g0 * xo.y);
        o.z = fmaf(gk, h.z, g0 * xo.z);
        o.w = fmaf(gk, h.w, g0 * xo.w);
    } else {
        o = ((float4*)out)[g];
        o.x = fmaf(gk, h.x, o.x);
        o.y = fmaf(gk, h.y, o.y);
        o.z = fmaf(gk, h.z, o.z);
        o.w = fmaf(gk, h.w, o.w);
    }
    ((float4*)out)[g] = o;
    if (k != STEPS - 1) {
        ((float4*)p_out)[g] = make_float4(dv * h.x, dv * h.y, dv * h.z, dv * h.w);
    }
}

// ---------- launch ----------

static inline size_t align_up(size_t v, size_t a) { return (v + a - 1) & ~(a - 1); }

extern "C" void kernel_launch(void* const* d_in, const int* in_sizes, int n_in,
                              void* d_out, int out_size, void* d_ws, size_t ws_size,
                              hipStream_t stream) {
    const float* x     = (const float*)d_in[0];
    const int*   ei    = (const int*)d_in[1];      // int32 per harness conversion
    const float* gamma = (const float*)d_in[2];
    float*       out   = (float*)d_out;

    const int n  = N_NODES;
    const int ne = N_EDGES;
    const int nblk_nodes = (n + 255) / 256;          // 196
    const int ne_pad_max = ne + 4 * n;               // padded CSR capacity (1.0M)

    // workspace carve-up (256B aligned), ~43 MB
    char*  ws  = (char*)d_ws;
    size_t off = 0;
    int*   deg      = (int*)(ws + off);   off = align_up(off + (size_t)n * 4, 256);
    int*   row_ptr  = (int*)(ws + off);   off = align_up(off + (size_t)(n + 1) * 4, 256);
    int*   partials = (int*)(ws + off);   off = align_up(off + (size_t)nblk_nodes * 4, 256);
    float* dinv     = (float*)(ws + off); off = align_up(off + (size_t)n * 4, 256);
    int*   csr_src  = (int*)(ws + off);   off = align_up(off + (size_t)ne_pad_max * 4, 256);
    float* pA       = (float*)(ws + off); off = align_up(off + (size_t)(n + 1) * CH * 4, 256);
    float* pB       = (float*)(ws + off); off = align_up(off + (size_t)(n + 1) * CH * 4, 256);
    (void)ws_size;

    (void)hipMemsetAsync(deg, 0, (size_t)n * 4, stream);

    const int nblk_e4 = (ne / 4 + 255) / 256;        // 782
    count_deg<<<nblk_e4, 256, 0, stream>>>(ei, deg, ne);

    scan1<<<nblk_nodes, 256, 0, stream>>>(deg, row_ptr, partials, dinv, n);
    scan2<<<1, 256, 0, stream>>>(partials, nblk_nodes);
    scan3<<<nblk_nodes, 256, 0, stream>>>(row_ptr, partials, n);

    pad_fill<<<nblk_nodes, 256, 0, stream>>>(deg, row_ptr, csr_src, n);
    fill_csr<<<nblk_e4, 256, 0, stream>>>(ei, row_ptr, deg, csr_src, ne);

    const int n4 = n * C4;                            // 1.2M float4s
    const int nblk_pre = (n4 + C4 + 255) / 256;       // covers sentinel row too
    prescale<<<nblk_pre, 256, 0, stream>>>(x, dinv, pA, pB);

    const int nblk_n4 = (n4 + 255) / 256;             // 4688
    const float* pin = pA;
    float* pout = pB;
    for (int k = 0; k < STEPS; ++k) {
        prop<<<nblk_n4, 256, 0, stream>>>(pin, pout, out, x, row_ptr, csr_src, dinv, gamma, k);
        pin  = pout;
        pout = (pout == pB) ? pA : pB;
    }
}

// Round 7
// 434.948 us; speedup vs baseline: 1.5758x; 1.4431x over previous
//
#include <hip/hip_runtime.h>
#include <hip/hip_fp16.h>

#define N_NODES 50000
#define N_EDGES 800000
#define CH 96
#define C8 12           // 16B fp16 chunks per row (8 channels each)
#define F4 24           // float4 chunks per fp32 row
#define STEPS 10
#define SENT N_NODES    // sentinel src row (kept all-zero in every p buffer)

// p buffer: (N_NODES+1) rows * 96 halves = 9,600,192 B -> 256B-aligned stride
#define PSTRIDE_BYTES 9600256
#define PSTRIDE_U4    (PSTRIDE_BYTES / 16)

// ---------- CSR build ----------

__global__ void count_deg(const int* __restrict__ ei, int* __restrict__ deg, int ne) {
    int t = blockIdx.x * blockDim.x + threadIdx.x;
    int e = t * 4;
    if (e < ne) {
        int4 d4 = *(const int4*)(ei + ne + e);
        if ((unsigned)d4.x < (unsigned)N_NODES) atomicAdd(&deg[d4.x], 1);
        if ((unsigned)d4.y < (unsigned)N_NODES) atomicAdd(&deg[d4.y], 1);
        if ((unsigned)d4.z < (unsigned)N_NODES) atomicAdd(&deg[d4.z], 1);
        if ((unsigned)d4.w < (unsigned)N_NODES) atomicAdd(&deg[d4.w], 1);
    }
}

// scan1 also computes dinv; row_ptr is built over PADDED degrees (round up to 4)
__global__ void scan1(const int* __restrict__ deg, int* __restrict__ row_ptr,
                      int* __restrict__ partials, float* __restrict__ dinv, int n) {
    __shared__ int sm[256];
    int i = blockIdx.x * 256 + threadIdx.x;
    int v = 0;
    if (i < n) {
        int d = deg[i];
        dinv[i] = (d > 0) ? (1.0f / sqrtf((float)d)) : 0.0f;
        v = (d + 3) & ~3;                      // padded degree
    }
    sm[threadIdx.x] = v;
    __syncthreads();
    for (int off = 1; off < 256; off <<= 1) {
        int t = (threadIdx.x >= off) ? sm[threadIdx.x - off] : 0;
        __syncthreads();
        sm[threadIdx.x] += t;
        __syncthreads();
    }
    if (i < n) row_ptr[i + 1] = sm[threadIdx.x];          // inclusive within chunk
    if (threadIdx.x == 255) partials[blockIdx.x] = sm[255];
}

__global__ void scan2(int* __restrict__ partials, int nb) {
    __shared__ int sm[256];
    int v = (threadIdx.x < nb) ? partials[threadIdx.x] : 0;
    sm[threadIdx.x] = v;
    __syncthreads();
    for (int off = 1; off < 256; off <<= 1) {
        int t = (threadIdx.x >= off) ? sm[threadIdx.x - off] : 0;
        __syncthreads();
        sm[threadIdx.x] += t;
        __syncthreads();
    }
    if (threadIdx.x < nb) partials[threadIdx.x] = sm[threadIdx.x] - v;  // exclusive
}

__global__ void scan3(int* __restrict__ row_ptr, const int* __restrict__ partials, int n) {
    int i = blockIdx.x * 256 + threadIdx.x;
    if (i < n) row_ptr[i + 1] += partials[blockIdx.x];
    if (i == 0) row_ptr[0] = 0;
}

// fill pad slots [deg, deg_padded) with sentinel BEFORE fill_csr consumes deg
__global__ void pad_fill(const int* __restrict__ deg, const int* __restrict__ row_ptr,
                         int* __restrict__ csr_src, int n) {
    int i = blockIdx.x * blockDim.x + threadIdx.x;
    if (i < n) {
        int dg = deg[i];
        int dp = (dg + 3) & ~3;
        int base = row_ptr[i];
        for (int j = dg; j < dp; ++j) csr_src[base + j] = SENT;
    }
}

// scatter src into dst-grouped slots; deg doubles as cursor via atomicSub
__global__ void fill_csr(const int* __restrict__ ei, const int* __restrict__ row_ptr,
                         int* __restrict__ deg, int* __restrict__ csr_src, int ne) {
    int t = blockIdx.x * blockDim.x + threadIdx.x;
    int e = t * 4;
    if (e < ne) {
        int4 s4 = *(const int4*)(ei + e);
        int4 d4 = *(const int4*)(ei + ne + e);
        #pragma unroll
        for (int j = 0; j < 4; ++j) {
            int s = (j == 0) ? s4.x : (j == 1) ? s4.y : (j == 2) ? s4.z : s4.w;
            int d = (j == 0) ? d4.x : (j == 1) ? d4.y : (j == 2) ? d4.z : d4.w;
            if ((unsigned)d >= (unsigned)N_NODES) continue;
            if ((unsigned)s >= (unsigned)N_NODES) s = SENT;
            int slot = atomicSub(&deg[d], 1) - 1;
            csr_src[row_ptr[d] + slot] = s;
        }
    }
}

// p0 = fp16(dinv ⊙ x)
__global__ void prescale16(const float* __restrict__ x, const float* __restrict__ dinv,
                           uint4* __restrict__ p0) {
    int g = blockIdx.x * blockDim.x + threadIdx.x;
    if (g >= N_NODES * C8) return;
    int node = g / C8;
    int c8   = g - node * C8;
    float dv = dinv[node];
    float4 x0 = ((const float4*)x)[node * F4 + c8 * 2];
    float4 x1 = ((const float4*)x)[node * F4 + c8 * 2 + 1];
    uint4 q;
    ((__half2*)&q)[0] = __floats2half2_rn(dv * x0.x, dv * x0.y);
    ((__half2*)&q)[1] = __floats2half2_rn(dv * x0.z, dv * x0.w);
    ((__half2*)&q)[2] = __floats2half2_rn(dv * x1.x, dv * x1.y);
    ((__half2*)&q)[3] = __floats2half2_rn(dv * x1.z, dv * x1.w);
    p0[g] = q;
}

// zero the sentinel row of every p buffer
__global__ void zero_sent(uint4* __restrict__ p_base, int nbuf) {
    int t = blockIdx.x * blockDim.x + threadIdx.x;
    if (t < nbuf * C8) {
        uint4 z = {0u, 0u, 0u, 0u};
        p_base[(size_t)(t / C8) * PSTRIDE_U4 + (size_t)SENT * C8 + (t % C8)] = z;
    }
}

__device__ inline void acc_add(float* a, uint4 q) {
    const __half2* h = (const __half2*)&q;
    #pragma unroll
    for (int i = 0; i < 4; ++i) {
        float2 f = __half22float2(h[i]);
        a[2 * i]     += f.x;
        a[2 * i + 1] += f.y;
    }
}

// ---------- propagation (fp16 storage, fp32 accumulate) ----------
// p_in = fp16(dinv ⊙ h_k). S = Σ p_in[src]; h_{k+1} = dinv*S; p_out = dinv*h_{k+1}.
// out != nullptr -> per-step out RMW (fallback mode); k==0 fuses gamma0*x.
// pout may be nullptr (last fallback step).
__global__ __launch_bounds__(256) void prop16(const uint4* __restrict__ p_in,
                                              uint4* __restrict__ p_out,
                                              float* __restrict__ out,
                                              const float* __restrict__ x,
                                              const int* __restrict__ row_ptr,
                                              const int* __restrict__ csr_src,
                                              const float* __restrict__ dinv,
                                              const float* __restrict__ gamma, int k) {
    int g = blockIdx.x * blockDim.x + threadIdx.x;
    if (g >= N_NODES * C8) return;
    int node = g / C8;
    int c8   = g - node * C8;
    int beg = row_ptr[node];
    int end = row_ptr[node + 1];          // multiple of 4 by construction

    float acc[8] = {0.f, 0.f, 0.f, 0.f, 0.f, 0.f, 0.f, 0.f};

    for (int e = beg; e < end; e += 4) {
        int4 m = *(const int4*)(csr_src + e);     // 4 src indices, one 16B load
        uint4 q0 = p_in[m.x * C8 + c8];
        uint4 q1 = p_in[m.y * C8 + c8];
        uint4 q2 = p_in[m.z * C8 + c8];
        uint4 q3 = p_in[m.w * C8 + c8];
        acc_add(acc, q0);
        acc_add(acc, q1);
        acc_add(acc, q2);
        acc_add(acc, q3);
    }

    float dv  = dinv[node];
    float dv2 = dv * dv;

    if (p_out) {
        uint4 q;
        ((__half2*)&q)[0] = __floats2half2_rn(dv2 * acc[0], dv2 * acc[1]);
        ((__half2*)&q)[1] = __floats2half2_rn(dv2 * acc[2], dv2 * acc[3]);
        ((__half2*)&q)[2] = __floats2half2_rn(dv2 * acc[4], dv2 * acc[5]);
        ((__half2*)&q)[3] = __floats2half2_rn(dv2 * acc[6], dv2 * acc[7]);
        p_out[g] = q;
    }

    if (out) {   // fallback: per-step out accumulation
        float gk = gamma[k + 1] * dv;            // out += gamma*(dv*S)
        int ob = node * F4 + c8 * 2;
        float4 o0, o1;
        if (k == 0) {
            float g0 = gamma[0];
            float4 x0 = ((const float4*)x)[ob];
            float4 x1 = ((const float4*)x)[ob + 1];
            o0.x = fmaf(gk, acc[0], g0 * x0.x); o0.y = fmaf(gk, acc[1], g0 * x0.y);
            o0.z = fmaf(gk, acc[2], g0 * x0.z); o0.w = fmaf(gk, acc[3], g0 * x0.w);
            o1.x = fmaf(gk, acc[4], g0 * x1.x); o1.y = fmaf(gk, acc[5], g0 * x1.y);
            o1.z = fmaf(gk, acc[6], g0 * x1.z); o1.w = fmaf(gk, acc[7], g0 * x1.w);
        } else {
            o0 = ((float4*)out)[ob];
            o1 = ((float4*)out)[ob + 1];
            o0.x = fmaf(gk, acc[0], o0.x); o0.y = fmaf(gk, acc[1], o0.y);
            o0.z = fmaf(gk, acc[2], o0.z); o0.w = fmaf(gk, acc[3], o0.w);
            o1.x = fmaf(gk, acc[4], o1.x); o1.y = fmaf(gk, acc[5], o1.y);
            o1.z = fmaf(gk, acc[6], o1.z); o1.w = fmaf(gk, acc[7], o1.w);
        }
        ((float4*)out)[ob]     = o0;
        ((float4*)out)[ob + 1] = o1;
    }
}

// deferred mode: out = gamma0*x + sum_{k=1..STEPS} gamma_k * (p_k / dinv)
__global__ __launch_bounds__(256) void finalize(const uint4* __restrict__ p_base,
                                                const float* __restrict__ x,
                                                const float* __restrict__ dinv,
                                                const float* __restrict__ gamma,
                                                float* __restrict__ out) {
    int g = blockIdx.x * blockDim.x + threadIdx.x;
    if (g >= N_NODES * C8) return;
    int node = g / C8;
    int c8   = g - node * C8;
    float dv  = dinv[node];
    float rdv = (dv > 0.f) ? (1.f / dv) : 0.f;

    int ob = node * F4 + c8 * 2;
    float g0 = gamma[0];
    float4 x0 = ((const float4*)x)[ob];
    float4 x1 = ((const float4*)x)[ob + 1];
    float o[8] = {g0 * x0.x, g0 * x0.y, g0 * x0.z, g0 * x0.w,
                  g0 * x1.x, g0 * x1.y, g0 * x1.z, g0 * x1.w};

    const uint4* p = p_base + (size_t)PSTRIDE_U4 + g;     // p_1
    for (int k = 1; k <= STEPS; ++k) {
        uint4 q = *p;
        p += (size_t)PSTRIDE_U4;
        float gk = gamma[k] * rdv;
        const __half2* h = (const __half2*)&q;
        #pragma unroll
        for (int i = 0; i < 4; ++i) {
            float2 f = __half22float2(h[i]);
            o[2 * i]     = fmaf(gk, f.x, o[2 * i]);
            o[2 * i + 1] = fmaf(gk, f.y, o[2 * i + 1]);
        }
    }
    float4 o0 = {o[0], o[1], o[2], o[3]};
    float4 o1 = {o[4], o[5], o[6], o[7]};
    ((float4*)out)[ob]     = o0;
    ((float4*)out)[ob + 1] = o1;
}

// ---------- launch ----------

static inline size_t align_up(size_t v, size_t a) { return (v + a - 1) & ~(a - 1); }

extern "C" void kernel_launch(void* const* d_in, const int* in_sizes, int n_in,
                              void* d_out, int out_size, void* d_ws, size_t ws_size,
                              hipStream_t stream) {
    const float* x     = (const float*)d_in[0];
    const int*   ei    = (const int*)d_in[1];      // int32 per harness conversion
    const float* gamma = (const float*)d_in[2];
    float*       out   = (float*)d_out;

    const int n  = N_NODES;
    const int ne = N_EDGES;
    const int nblk_nodes = (n + 255) / 256;          // 196
    const int ne_pad_max = ne + 4 * n;               // padded CSR capacity (1.0M)

    char*  ws  = (char*)d_ws;
    size_t off = 0;
    int*   deg      = (int*)(ws + off);   off = align_up(off + (size_t)n * 4, 256);
    int*   row_ptr  = (int*)(ws + off);   off = align_up(off + (size_t)(n + 1) * 4, 256);
    int*   partials = (int*)(ws + off);   off = align_up(off + (size_t)nblk_nodes * 4, 256);
    float* dinv     = (float*)(ws + off); off = align_up(off + (size_t)n * 4, 256);
    int*   csr_src  = (int*)(ws + off);   off = align_up(off + (size_t)ne_pad_max * 4, 256);
    uint4* p_base   = (uint4*)(ws + off);

    // deferred mode needs 11 p buffers (p_0 .. p_10); fallback needs 2
    const bool deferred = (ws_size >= off + 11ull * PSTRIDE_BYTES);
    const int  nbuf     = deferred ? 11 : 2;

    (void)hipMemsetAsync(deg, 0, (size_t)n * 4, stream);

    const int nblk_e4 = (ne / 4 + 255) / 256;        // 782
    count_deg<<<nblk_e4, 256, 0, stream>>>(ei, deg, ne);

    scan1<<<nblk_nodes, 256, 0, stream>>>(deg, row_ptr, partials, dinv, n);
    scan2<<<1, 256, 0, stream>>>(partials, nblk_nodes);
    scan3<<<nblk_nodes, 256, 0, stream>>>(row_ptr, partials, n);

    pad_fill<<<nblk_nodes, 256, 0, stream>>>(deg, row_ptr, csr_src, n);
    fill_csr<<<nblk_e4, 256, 0, stream>>>(ei, row_ptr, deg, csr_src, ne);

    const int ng = n * C8;                            // 600K threads
    const int nblk_g = (ng + 255) / 256;              // 2344
    prescale16<<<nblk_g, 256, 0, stream>>>(x, dinv, p_base);
    zero_sent<<<1, 256, 0, stream>>>(p_base, nbuf);

    if (deferred) {
        for (int k = 0; k < STEPS; ++k) {
            const uint4* pin  = p_base + (size_t)k * PSTRIDE_U4;
            uint4*       pout = p_base + (size_t)(k + 1) * PSTRIDE_U4;
            prop16<<<nblk_g, 256, 0, stream>>>(pin, pout, nullptr, x,
                                               row_ptr, csr_src, dinv, gamma, k);
        }
        finalize<<<nblk_g, 256, 0, stream>>>(p_base, x, dinv, gamma, out);
    } else {
        uint4* pA = p_base;
        uint4* pB = p_base + (size_t)PSTRIDE_U4;
        const uint4* pin = pA;
        uint4* pout = pB;
        for (int k = 0; k < STEPS; ++k) {
            uint4* pw = (k == STEPS - 1) ? nullptr : pout;
            prop16<<<nblk_g, 256, 0, stream>>>(pin, pw, out, x,
                                               row_ptr, csr_src, dinv, gamma, k);
            pin  = pout;
            pout = (pout == pB) ? pA : pB;
        }
    }
}